// Round 5
// baseline (239.541 us; speedup 1.0000x reference)
//
#include <hip/hip_runtime.h>
#include <hip/hip_bf16.h>

#define TOK 16384
#define HD  1024
#define DD  256
#define NE  8

typedef __attribute__((ext_vector_type(8))) short short8;
typedef __attribute__((ext_vector_type(4))) float floatx4;
typedef unsigned short u16;

static __device__ __forceinline__ u16 f2bf(float f) {
  __hip_bfloat16 h = __float2bfloat16(f);
  return *reinterpret_cast<u16*>(&h);
}
static __device__ __forceinline__ short8 cvt8(const float* p) {
  float4 a = *(const float4*)p;
  float4 b = *(const float4*)(p + 4);
  u16 t[8] = {f2bf(a.x), f2bf(a.y), f2bf(a.z), f2bf(a.w),
              f2bf(b.x), f2bf(b.y), f2bf(b.z), f2bf(b.w)};
  return *(short8*)t;
}

// ---- prep: blocks 0..1535 transpose weights -> bf16 K-contiguous;
//            blocks 1536..2559 router (16 tokens each) + optional x->bf16 emit.
__global__ __launch_bounds__(256) void prep_kernel(
    const float* __restrict__ wg, const float* __restrict__ wu,
    const float* __restrict__ wd, const float* __restrict__ x,
    const float* __restrict__ gw,
    u16* __restrict__ wgT, u16* __restrict__ wuT, u16* __restrict__ wdT,
    int* __restrict__ counts, int* __restrict__ tlist,
    u16* __restrict__ xb, int use_xb)
{
  __shared__ u16 tile[64][72];
  __shared__ int sexp[16];
  __shared__ int sbase[NE];
  int bid = blockIdx.x;
  int tid = threadIdx.x;

  if (bid < 1536) {
    const float* src; u16* dst; int R, C;
    if (bid < 512)       { src = wg; dst = wgT; R = HD; C = DD; }
    else if (bid < 1024) { src = wu; dst = wuT; R = HD; C = DD; bid -= 512; }
    else                 { src = wd; dst = wdT; R = DD; C = HD; bid -= 1024; }
    int e = bid >> 6, t = bid & 63;
    int ntc = C >> 6;
    int tr = t / ntc, tc = t % ntc;
    int r = tid >> 2, c0 = (tid & 3) * 16;
    const float* s = src + (size_t)e * R * C + (size_t)(tr * 64 + r) * C + tc * 64 + c0;
    *(short8*)&tile[r][c0]     = cvt8(s);
    *(short8*)&tile[r][c0 + 8] = cvt8(s + 8);
    __syncthreads();
    int c = tid >> 2, r0 = (tid & 3) * 16;
    alignas(16) u16 buf[16];
    for (int j = 0; j < 16; ++j) buf[j] = tile[r0 + j][c];
    u16* d = dst + (size_t)e * R * C + (size_t)(tc * 64 + c) * R + tr * 64 + r0;
    *(float4*)(d)     = *(const float4*)&buf[0];
    *(float4*)(d + 8) = *(const float4*)&buf[8];
    return;
  }

  // ---- router: 16 tokens per block, 4 per wave; fp32-exact logits
  int lane = tid & 63, wave = tid >> 6;
  int tok0 = (bid - 1536) * 16;
  for (int i = 0; i < 4; ++i) {
    int ti = wave * 4 + i;
    int t = tok0 + ti;
    const float* xp = x + (size_t)t * HD + lane * 16;
    float4 x0 = *(const float4*)xp,       x1 = *(const float4*)(xp + 4);
    float4 x2 = *(const float4*)(xp + 8), x3 = *(const float4*)(xp + 12);
    float acc[NE];
    for (int e = 0; e < NE; ++e) {
      const float* gp = gw + e * HD + lane * 16;
      float4 g0 = *(const float4*)gp,       g1 = *(const float4*)(gp + 4);
      float4 g2 = *(const float4*)(gp + 8), g3 = *(const float4*)(gp + 12);
      acc[e] = x0.x*g0.x + x0.y*g0.y + x0.z*g0.z + x0.w*g0.w
             + x1.x*g1.x + x1.y*g1.y + x1.z*g1.z + x1.w*g1.w
             + x2.x*g2.x + x2.y*g2.y + x2.z*g2.z + x2.w*g2.w
             + x3.x*g3.x + x3.y*g3.y + x3.z*g3.z + x3.w*g3.w;
    }
    for (int off = 32; off >= 1; off >>= 1)
      for (int e = 0; e < NE; ++e) acc[e] += __shfl_xor(acc[e], off, 64);
    if (lane == 0) {
      int be = 0; float bv = acc[0];
      for (int e = 1; e < NE; ++e) if (acc[e] > bv) { bv = acc[e]; be = e; }
      sexp[ti] = be;
    }
    if (use_xb) {
      alignas(16) u16 b[16] = {f2bf(x0.x), f2bf(x0.y), f2bf(x0.z), f2bf(x0.w),
                               f2bf(x1.x), f2bf(x1.y), f2bf(x1.z), f2bf(x1.w),
                               f2bf(x2.x), f2bf(x2.y), f2bf(x2.z), f2bf(x2.w),
                               f2bf(x3.x), f2bf(x3.y), f2bf(x3.z), f2bf(x3.w)};
      u16* op = xb + (size_t)t * HD + lane * 16;
      *(float4*)op       = *(const float4*)&b[0];
      *(float4*)(op + 8) = *(const float4*)&b[8];
    }
  }
  __syncthreads();
  if (tid < NE) {
    int c = 0;
    for (int i = 0; i < 16; ++i) c += (sexp[i] == tid) ? 1 : 0;
    sbase[tid] = c ? atomicAdd(&counts[tid], c) : 0;
  }
  __syncthreads();
  if (tid < 16) {
    int e = sexp[tid], rank = 0;
    for (int i = 0; i < tid; ++i) rank += (sexp[i] == e) ? 1 : 0;
    tlist[e * TOK + sbase[e] + rank] = tok0 + tid;
  }
}

// ---- gemm1 core (templated on A dtype path): gathered A @ [g-half ++ u-half],
// epilogue relu(g)^2*u staged in LDS -> coalesced inter stores.
// flat grid 4096: e=bid&7 (XCD locality), half=(bid>>3)&1, tile=bid>>4 (64 tokens)
template <int USE_XB>
static __device__ __forceinline__ void gemm1_body(
    const float* __restrict__ x, const u16* __restrict__ xb,
    const u16* __restrict__ wgT, const u16* __restrict__ wuT,
    const int* __restrict__ counts, const int* __restrict__ tlist,
    u16* __restrict__ inter)
{
  int bid = blockIdx.x;
  int e = bid & 7, half = (bid >> 3) & 1, tile = bid >> 4;
  int cnt = counts[e];
  int row0 = tile * 64;
  if (row0 >= cnt) return;

  __shared__ int stok[64];
  __shared__ __align__(16) u16 sB[256][40];   // 20480 B; reused as st[64][136] (17408 B)

  int tid = threadIdx.x, lane = tid & 63, wave = tid >> 6;
  if (tid < 64) {
    int r = row0 + tid;
    stok[tid] = tlist[e * TOK + (r < cnt ? r : cnt - 1)];
  }
  __syncthreads();
  int rmax = cnt - row0; if (rmax > 64) rmax = 64;

  int col = lane & 15, quad = lane >> 4;

  // direct A-fragment row pointers (MFMA A: row=lane&15, k=quad*8+j)
  const u16*   arow_b[4];
  const float* arow_f[4];
  for (int m = 0; m < 4; ++m) {
    int t = stok[m * 16 + col];
    if (USE_XB) arow_b[m] = xb + (size_t)t * HD + quad * 8;
    else        arow_f[m] = x  + (size_t)t * HD + quad * 8;
  }

  const u16* bp[4];
  for (int i = 0; i < 4; ++i) {
    int id = i * 256 + tid;
    int n = id >> 2, c = (id & 3) * 8;
    const u16* base = (n < 128) ? (wgT + ((size_t)e * DD + half * 128 + n) * HD)
                                : (wuT + ((size_t)e * DD + half * 128 + (n - 128)) * HD);
    bp[i] = base + c;
  }

  floatx4 acc[4][4];
  floatx4 zz = {0.f, 0.f, 0.f, 0.f};
  for (int m = 0; m < 4; ++m) for (int j = 0; j < 4; ++j) acc[m][j] = zz;

  for (int k0 = 0; k0 < HD; k0 += 32) {
    short8 af[4];
    for (int m = 0; m < 4; ++m)
      af[m] = USE_XB ? *(const short8*)(arow_b[m] + k0) : cvt8(arow_f[m] + k0);
    short8 bv[4];
    for (int i = 0; i < 4; ++i) bv[i] = *(const short8*)(bp[i] + k0);
    __syncthreads();
    for (int i = 0; i < 4; ++i) {
      int id = i * 256 + tid;
      *(short8*)&sB[id >> 2][(id & 3) * 8] = bv[i];
    }
    __syncthreads();
    short8 bfr[4];
    bfr[0] = *(const short8*)&sB[wave * 32 + col][quad * 8];
    bfr[1] = *(const short8*)&sB[wave * 32 + 16 + col][quad * 8];
    bfr[2] = *(const short8*)&sB[128 + wave * 32 + col][quad * 8];
    bfr[3] = *(const short8*)&sB[128 + wave * 32 + 16 + col][quad * 8];
    for (int m = 0; m < 4; ++m)
      for (int j = 0; j < 4; ++j)
        acc[m][j] = __builtin_amdgcn_mfma_f32_16x16x32_bf16(af[m], bfr[j], acc[m][j], 0, 0, 0);
  }

  // epilogue: relu(g)^2*u -> LDS stage -> 16B/lane coalesced stores
  __syncthreads();
  u16 (*st)[136] = (u16(*)[136])sB;
  for (int m = 0; m < 4; ++m)
    for (int jj = 0; jj < 2; ++jj)
      for (int r = 0; r < 4; ++r) {
        int row = m * 16 + quad * 4 + r;     // C layout: col=lane&15, row=quad*4+reg
        float g = acc[m][jj][r]; g = g > 0.f ? g : 0.f;
        st[row][wave * 32 + jj * 16 + col] = f2bf(g * g * acc[m][jj + 2][r]);
      }
  __syncthreads();
  for (int i = 0; i < 4; ++i) {
    int id = i * 256 + tid;
    int row = id >> 4, c = (id & 15) * 8;
    if (row < rmax)
      *(float4*)(inter + (size_t)stok[row] * DD + half * 128 + c) = *(const float4*)&st[row][c];
  }
}

__global__ __launch_bounds__(256) void gemm1_xb(
    const u16* __restrict__ xb, const u16* __restrict__ wgT, const u16* __restrict__ wuT,
    const int* __restrict__ counts, const int* __restrict__ tlist, u16* __restrict__ inter) {
  gemm1_body<1>(nullptr, xb, wgT, wuT, counts, tlist, inter);
}
__global__ __launch_bounds__(256) void gemm1_f32(
    const float* __restrict__ x, const u16* __restrict__ wgT, const u16* __restrict__ wuT,
    const int* __restrict__ counts, const int* __restrict__ tlist, u16* __restrict__ inter) {
  gemm1_body<0>(x, nullptr, wgT, wuT, counts, tlist, inter);
}

// ---- gemm2: gathered inter(bf16, direct A-frags) @ wdT -> out fp32 (LDS-staged stores)
// flat grid 8192: e=bid&7, q=(bid>>3)&3 (256-col quarter), tile=bid>>5 (64 tokens)
__global__ __launch_bounds__(256) void gemm2_kernel(
    const u16* __restrict__ inter, const u16* __restrict__ wdT,
    const int* __restrict__ counts, const int* __restrict__ tlist,
    float* __restrict__ out)
{
  int bid = blockIdx.x;
  int e = bid & 7, q = (bid >> 3) & 3, tile = bid >> 5;
  int cnt = counts[e];
  int row0 = tile * 64;
  if (row0 >= cnt) return;
  int n0 = q * 256;

  __shared__ int stok[64];
  __shared__ __align__(16) u16 sBraw[256 * 40];   // 20480 B; reused as float st[16][260]
  u16 (*sB)[40] = (u16(*)[40])sBraw;
  float (*st)[260] = (float(*)[260])sBraw;        // 16640 B

  int tid = threadIdx.x, lane = tid & 63, wave = tid >> 6;
  if (tid < 64) {
    int r = row0 + tid;
    stok[tid] = tlist[e * TOK + (r < cnt ? r : cnt - 1)];
  }
  __syncthreads();
  int rmax = cnt - row0; if (rmax > 64) rmax = 64;

  int col = lane & 15, quad = lane >> 4;

  const u16* arow[4];
  for (int m = 0; m < 4; ++m)
    arow[m] = inter + (size_t)stok[m * 16 + col] * DD + quad * 8;

  floatx4 acc[4][4];
  floatx4 zz = {0.f, 0.f, 0.f, 0.f};
  for (int m = 0; m < 4; ++m) for (int j = 0; j < 4; ++j) acc[m][j] = zz;

  for (int k0 = 0; k0 < DD; k0 += 32) {
    short8 af[4];
    for (int m = 0; m < 4; ++m) af[m] = *(const short8*)(arow[m] + k0);
    short8 bv[4];
    for (int i = 0; i < 4; ++i) {
      int id = i * 256 + tid;
      int n = id >> 2, c = (id & 3) * 8;
      bv[i] = *(const short8*)(wdT + ((size_t)e * HD + n0 + n) * DD + k0 + c);
    }
    __syncthreads();
    for (int i = 0; i < 4; ++i) {
      int id = i * 256 + tid;
      *(short8*)&sB[id >> 2][(id & 3) * 8] = bv[i];
    }
    __syncthreads();
    short8 bfr[4];
    for (int j = 0; j < 4; ++j) bfr[j] = *(const short8*)&sB[wave * 64 + j * 16 + col][quad * 8];
    for (int m = 0; m < 4; ++m)
      for (int j = 0; j < 4; ++j)
        acc[m][j] = __builtin_amdgcn_mfma_f32_16x16x32_bf16(af[m], bfr[j], acc[m][j], 0, 0, 0);
  }

  // epilogue: 16 rows x 256 fp32 at a time through LDS -> 1KB/row coalesced stores
  for (int m = 0; m < 4; ++m) {
    __syncthreads();
    for (int j = 0; j < 4; ++j)
      for (int r = 0; r < 4; ++r)
        st[quad * 4 + r][wave * 64 + j * 16 + col] = acc[m][j][r];
    __syncthreads();
    for (int i = 0; i < 4; ++i) {
      int id = i * 256 + tid;
      int r = id >> 6, c4 = (id & 63) * 4;
      int row = m * 16 + r;
      if (row < rmax)
        *(float4*)(out + (size_t)stok[row] * HD + n0 + c4) = *(const float4*)&st[r][c4];
    }
  }
}

// ---------------- launch ---------------------------------------------------
extern "C" void kernel_launch(void* const* d_in, const int* in_sizes, int n_in,
                              void* d_out, int out_size, void* d_ws, size_t ws_size,
                              hipStream_t stream) {
  const float* x  = (const float*)d_in[0];
  const float* gw = (const float*)d_in[1];
  const float* wg = (const float*)d_in[2];
  const float* wu = (const float*)d_in[3];
  const float* wd = (const float*)d_in[4];
  float* out = (float*)d_out;

  char* ws = (char*)d_ws;
  int* counts = (int*)ws;                        // 256 B
  int* tlist  = (int*)(ws + 256);                // 512 KB
  u16* wgT   = (u16*)(ws + 524544);              // 4 MB
  u16* wuT   = wgT + (size_t)NE * DD * HD;       // 4 MB
  u16* wdT   = wuT + (size_t)NE * DD * HD;       // 4 MB
  u16* inter = wdT + (size_t)NE * HD * DD;       // 8 MB  (ends ~21.0 MB)
  u16* xb    = inter + (size_t)TOK * DD;         // 32 MB (ends ~53.5 MB)
  size_t need_xb = 524544 + (size_t)NE * DD * HD * 2 * 3
                 + (size_t)TOK * DD * 2 + (size_t)TOK * HD * 2;
  int use_xb = (ws_size >= need_xb) ? 1 : 0;

  hipMemsetAsync(counts, 0, NE * sizeof(int), stream);
  prep_kernel<<<2560, 256, 0, stream>>>(wg, wu, wd, x, gw, wgT, wuT, wdT,
                                        counts, tlist, xb, use_xb);
  if (use_xb)
    gemm1_xb<<<4096, 256, 0, stream>>>(xb, wgT, wuT, counts, tlist, inter);
  else
    gemm1_f32<<<4096, 256, 0, stream>>>(x, wgT, wuT, counts, tlist, inter);
  gemm2_kernel<<<8192, 256, 0, stream>>>(inter, wdT, counts, tlist, out);
}